// Round 1
// baseline (123.870 us; speedup 1.0000x reference)
//
#include <hip/hip_runtime.h>
#include <cfloat>

// One 64-lane wave per row of 1024 floats.
// Row layout per lane: lane holds floats at indices j*256 + lane*4 + {0..3}, j=0..3
// (each float4 load is 64 lanes x 16B = 1024B contiguous -> perfectly coalesced).

static __device__ __forceinline__ float wave_max64(float v) {
#pragma unroll
    for (int d = 1; d < 64; d <<= 1) v = fmaxf(v, __shfl_xor(v, d));
    return v;
}

static __device__ __forceinline__ float wave_sum64(float v) {
#pragma unroll
    for (int d = 1; d < 64; d <<= 1) v += __shfl_xor(v, d);
    return v;
}

__global__ __launch_bounds__(256) void kmax_norm_kernel(const float* __restrict__ in,
                                                        float* __restrict__ out,
                                                        int nrows) {
    const int lane = threadIdx.x & 63;
    const int wid  = threadIdx.x >> 6;
    const int row  = blockIdx.x * 4 + wid;
    if (row >= nrows) return;

    const float4* __restrict__ rp = reinterpret_cast<const float4*>(in) + (size_t)row * 256;
    float4* __restrict__ op       = reinterpret_cast<float4*>(out) + (size_t)row * 256;

    const float4 v0 = rp[lane];
    const float4 v1 = rp[64 + lane];
    const float4 v2 = rp[128 + lane];
    const float4 v3 = rp[192 + lane];

    // Destructible working copy (all static indices -> stays in VGPRs).
    float w[16];
    w[0]  = v0.x; w[1]  = v0.y; w[2]  = v0.z; w[3]  = v0.w;
    w[4]  = v1.x; w[5]  = v1.y; w[6]  = v1.z; w[7]  = v1.w;
    w[8]  = v2.x; w[9]  = v2.y; w[10] = v2.z; w[11] = v2.w;
    w[12] = v3.x; w[13] = v3.y; w[14] = v3.z; w[15] = v3.w;

    float lmax = w[0];
#pragma unroll
    for (int e = 1; e < 16; ++e) lmax = fmaxf(lmax, w[e]);

    // 16 rounds of global max extraction; after round it, kth == (it+1)-th largest.
    float kth = 0.0f;
    for (int it = 0; it < 16; ++it) {
        const float g = wave_max64(lmax);
        kth = g;
        const unsigned long long b = __ballot(lmax == g);
        const int first = __ffsll(b) - 1;
        if (lane == first) {
            // Remove exactly one occurrence of g from this lane, recompute local max.
            bool rm = false;
            float nm = -FLT_MAX;
#pragma unroll
            for (int e = 0; e < 16; ++e) {
                const bool hit = (!rm) && (w[e] == g);
                w[e] = hit ? -FLT_MAX : w[e];
                rm = rm || hit;
                nm = fmaxf(nm, w[e]);
            }
            lmax = nm;
        }
    }

    // Sum of kept values (x >= kth), wave-wide.
    float s = 0.0f;
    s += (v0.x >= kth) ? v0.x : 0.0f;
    s += (v0.y >= kth) ? v0.y : 0.0f;
    s += (v0.z >= kth) ? v0.z : 0.0f;
    s += (v0.w >= kth) ? v0.w : 0.0f;
    s += (v1.x >= kth) ? v1.x : 0.0f;
    s += (v1.y >= kth) ? v1.y : 0.0f;
    s += (v1.z >= kth) ? v1.z : 0.0f;
    s += (v1.w >= kth) ? v1.w : 0.0f;
    s += (v2.x >= kth) ? v2.x : 0.0f;
    s += (v2.y >= kth) ? v2.y : 0.0f;
    s += (v2.z >= kth) ? v2.z : 0.0f;
    s += (v2.w >= kth) ? v2.w : 0.0f;
    s += (v3.x >= kth) ? v3.x : 0.0f;
    s += (v3.y >= kth) ? v3.y : 0.0f;
    s += (v3.z >= kth) ? v3.z : 0.0f;
    s += (v3.w >= kth) ? v3.w : 0.0f;
    s = wave_sum64(s);

    const float inv = 1.0f / s;

    float4 o;
    o.x = (v0.x >= kth) ? v0.x * inv : 0.0f;
    o.y = (v0.y >= kth) ? v0.y * inv : 0.0f;
    o.z = (v0.z >= kth) ? v0.z * inv : 0.0f;
    o.w = (v0.w >= kth) ? v0.w * inv : 0.0f;
    op[lane] = o;
    o.x = (v1.x >= kth) ? v1.x * inv : 0.0f;
    o.y = (v1.y >= kth) ? v1.y * inv : 0.0f;
    o.z = (v1.z >= kth) ? v1.z * inv : 0.0f;
    o.w = (v1.w >= kth) ? v1.w * inv : 0.0f;
    op[64 + lane] = o;
    o.x = (v2.x >= kth) ? v2.x * inv : 0.0f;
    o.y = (v2.y >= kth) ? v2.y * inv : 0.0f;
    o.z = (v2.z >= kth) ? v2.z * inv : 0.0f;
    o.w = (v2.w >= kth) ? v2.w * inv : 0.0f;
    op[128 + lane] = o;
    o.x = (v3.x >= kth) ? v3.x * inv : 0.0f;
    o.y = (v3.y >= kth) ? v3.y * inv : 0.0f;
    o.z = (v3.z >= kth) ? v3.z * inv : 0.0f;
    o.w = (v3.w >= kth) ? v3.w * inv : 0.0f;
    op[192 + lane] = o;
}

extern "C" void kernel_launch(void* const* d_in, const int* in_sizes, int n_in,
                              void* d_out, int out_size, void* d_ws, size_t ws_size,
                              hipStream_t stream) {
    (void)n_in; (void)d_ws; (void)ws_size; (void)out_size;
    const float* in = (const float*)d_in[0];
    float* out = (float*)d_out;
    const int nrows = in_sizes[0] / 1024;           // 16*4096 = 65536
    const int blocks = (nrows + 3) / 4;             // 4 waves (rows) per 256-thread block
    kmax_norm_kernel<<<blocks, 256, 0, stream>>>(in, out, nrows);
}

// Round 3
// 89.566 us; speedup vs baseline: 1.3830x; 1.3830x over previous
//
#include <hip/hip_runtime.h>
#include <cfloat>

// One 64-lane wave per row of 1024 floats.
// Lane i owns floats j*256 + i*4 + {0..3}, j=0..3 (coalesced float4 loads).
//
// Selection: each lane sorts its 16 values descending ONCE (Batcher network,
// 63 compare-exchanges, all static indices -> pure VGPR). Then 15 rounds of
// {wave-max of heads, winner shifts its sorted list down by one}; the 16th
// wave-max of heads is kth.

typedef float f32x4 __attribute__((ext_vector_type(4)));

static __device__ __forceinline__ float wave_max64(float v) {
#pragma unroll
    for (int d = 1; d < 64; d <<= 1) v = fmaxf(v, __shfl_xor(v, d));
    return v;
}

static __device__ __forceinline__ float wave_sum64(float v) {
#pragma unroll
    for (int d = 1; d < 64; d <<= 1) v += __shfl_xor(v, d);
    return v;
}

__global__ __launch_bounds__(256) void kmax_norm_kernel(const float* __restrict__ in,
                                                        float* __restrict__ out,
                                                        int nrows) {
    const int lane = threadIdx.x & 63;
    const int wid  = threadIdx.x >> 6;
    const int row  = blockIdx.x * 4 + wid;
    if (row >= nrows) return;

    const float4* __restrict__ rp = reinterpret_cast<const float4*>(in) + (size_t)row * 256;
    f32x4* __restrict__ op        = reinterpret_cast<f32x4*>(out) + (size_t)row * 256;

    const float4 v0 = rp[lane];
    const float4 v1 = rp[64 + lane];
    const float4 v2 = rp[128 + lane];
    const float4 v3 = rp[192 + lane];

    float w0  = v0.x, w1  = v0.y, w2  = v0.z, w3  = v0.w;
    float w4  = v1.x, w5  = v1.y, w6  = v1.z, w7  = v1.w;
    float w8  = v2.x, w9  = v2.y, w10 = v2.z, w11 = v2.w;
    float w12 = v3.x, w13 = v3.y, w14 = v3.z, w15 = v3.w;

    // Batcher odd-even mergesort, 16 elements, descending (max lands at lower index).
#define CE(A, B) { const float ta_ = A, tb_ = B; A = fmaxf(ta_, tb_); B = fminf(ta_, tb_); }
    // sort pairs
    CE(w0,w1) CE(w2,w3) CE(w4,w5) CE(w6,w7) CE(w8,w9) CE(w10,w11) CE(w12,w13) CE(w14,w15)
    // merge 2->4
    CE(w0,w2) CE(w1,w3) CE(w4,w6) CE(w5,w7) CE(w8,w10) CE(w9,w11) CE(w12,w14) CE(w13,w15)
    CE(w1,w2) CE(w5,w6) CE(w9,w10) CE(w13,w14)
    // merge 4->8
    CE(w0,w4) CE(w1,w5) CE(w2,w6) CE(w3,w7)
    CE(w8,w12) CE(w9,w13) CE(w10,w14) CE(w11,w15)
    CE(w2,w4) CE(w3,w5) CE(w10,w12) CE(w11,w13)
    CE(w1,w2) CE(w3,w4) CE(w5,w6) CE(w9,w10) CE(w11,w12) CE(w13,w14)
    // merge 8->16
    CE(w0,w8) CE(w1,w9) CE(w2,w10) CE(w3,w11) CE(w4,w12) CE(w5,w13) CE(w6,w14) CE(w7,w15)
    CE(w4,w8) CE(w5,w9) CE(w6,w10) CE(w7,w11)
    CE(w2,w4) CE(w3,w5) CE(w6,w8) CE(w7,w9) CE(w10,w12) CE(w11,w13)
    CE(w1,w2) CE(w3,w4) CE(w5,w6) CE(w7,w8) CE(w9,w10) CE(w11,w12) CE(w13,w14)
#undef CE

    // 15 removal rounds: wave-max of heads; winner lane pops its head.
    for (int it = 0; it < 15; ++it) {
        const float g = wave_max64(w0);
        const unsigned long long b = __ballot(w0 == g);
        if (lane == __ffsll(b) - 1) {
            w0 = w1;  w1 = w2;   w2 = w3;   w3 = w4;
            w4 = w5;  w5 = w6;   w6 = w7;   w7 = w8;
            w8 = w9;  w9 = w10;  w10 = w11; w11 = w12;
            w12 = w13; w13 = w14; w14 = w15; w15 = -FLT_MAX;
        }
    }
    const float kth = wave_max64(w0);   // 16th largest

    // Sum of kept values (x >= kth), wave-wide.
    float s = 0.0f;
    s += (v0.x >= kth) ? v0.x : 0.0f;
    s += (v0.y >= kth) ? v0.y : 0.0f;
    s += (v0.z >= kth) ? v0.z : 0.0f;
    s += (v0.w >= kth) ? v0.w : 0.0f;
    s += (v1.x >= kth) ? v1.x : 0.0f;
    s += (v1.y >= kth) ? v1.y : 0.0f;
    s += (v1.z >= kth) ? v1.z : 0.0f;
    s += (v1.w >= kth) ? v1.w : 0.0f;
    s += (v2.x >= kth) ? v2.x : 0.0f;
    s += (v2.y >= kth) ? v2.y : 0.0f;
    s += (v2.z >= kth) ? v2.z : 0.0f;
    s += (v2.w >= kth) ? v2.w : 0.0f;
    s += (v3.x >= kth) ? v3.x : 0.0f;
    s += (v3.y >= kth) ? v3.y : 0.0f;
    s += (v3.z >= kth) ? v3.z : 0.0f;
    s += (v3.w >= kth) ? v3.w : 0.0f;
    s = wave_sum64(s);

    const float inv = 1.0f / s;

    f32x4 o;
    o.x = (v0.x >= kth) ? v0.x * inv : 0.0f;
    o.y = (v0.y >= kth) ? v0.y * inv : 0.0f;
    o.z = (v0.z >= kth) ? v0.z * inv : 0.0f;
    o.w = (v0.w >= kth) ? v0.w * inv : 0.0f;
    __builtin_nontemporal_store(o, &op[lane]);
    o.x = (v1.x >= kth) ? v1.x * inv : 0.0f;
    o.y = (v1.y >= kth) ? v1.y * inv : 0.0f;
    o.z = (v1.z >= kth) ? v1.z * inv : 0.0f;
    o.w = (v1.w >= kth) ? v1.w * inv : 0.0f;
    __builtin_nontemporal_store(o, &op[64 + lane]);
    o.x = (v2.x >= kth) ? v2.x * inv : 0.0f;
    o.y = (v2.y >= kth) ? v2.y * inv : 0.0f;
    o.z = (v2.z >= kth) ? v2.z * inv : 0.0f;
    o.w = (v2.w >= kth) ? v2.w * inv : 0.0f;
    __builtin_nontemporal_store(o, &op[128 + lane]);
    o.x = (v3.x >= kth) ? v3.x * inv : 0.0f;
    o.y = (v3.y >= kth) ? v3.y * inv : 0.0f;
    o.z = (v3.z >= kth) ? v3.z * inv : 0.0f;
    o.w = (v3.w >= kth) ? v3.w * inv : 0.0f;
    __builtin_nontemporal_store(o, &op[192 + lane]);
}

extern "C" void kernel_launch(void* const* d_in, const int* in_sizes, int n_in,
                              void* d_out, int out_size, void* d_ws, size_t ws_size,
                              hipStream_t stream) {
    (void)n_in; (void)d_ws; (void)ws_size; (void)out_size;
    const float* in = (const float*)d_in[0];
    float* out = (float*)d_out;
    const int nrows = in_sizes[0] / 1024;           // 16*4096 = 65536
    const int blocks = (nrows + 3) / 4;             // 4 waves (rows) per 256-thread block
    kmax_norm_kernel<<<blocks, 256, 0, stream>>>(in, out, nrows);
}

// Round 4
// 74.945 us; speedup vs baseline: 1.6528x; 1.1951x over previous
//
#include <hip/hip_runtime.h>
#include <cfloat>

// One 64-lane wave per row of 1024 floats; lane i owns j*256 + i*4 + {0..3}.
//
// kth selection (exact):
//   1. h = per-lane max; bitonic-sort the 64 h's across lanes (21 shfl stages).
//      t0 = 16th-largest head. Since those 16 heads are 16 distinct elements
//      >= t0, we have count(x >= t0) >= 16  =>  t0 <= kth. Candidates = {x >= t0}.
//   2. Ascend through distinct candidate values from the smallest:
//      g_next = wave_min(x > g); stop when count(x > g) <= 15 => g == kth.
//      (For any g < kth, count(x > g) >= count(x >= kth) >= 16, so no early stop;
//       g visits every distinct candidate value, and kth is one.)

typedef float f32x4 __attribute__((ext_vector_type(4)));

static __device__ __forceinline__ float wave_min64(float v) {
#pragma unroll
    for (int d = 1; d < 64; d <<= 1) v = fminf(v, __shfl_xor(v, d));
    return v;
}
static __device__ __forceinline__ float wave_sum64(float v) {
#pragma unroll
    for (int d = 1; d < 64; d <<= 1) v += __shfl_xor(v, d);
    return v;
}
static __device__ __forceinline__ int wave_sum64_i(int v) {
#pragma unroll
    for (int d = 1; d < 64; d <<= 1) v += __shfl_xor(v, d);
    return v;
}

__global__ __launch_bounds__(256) void kmax_norm_kernel(const float* __restrict__ in,
                                                        float* __restrict__ out,
                                                        int nrows) {
    const int lane = threadIdx.x & 63;
    const int wid  = threadIdx.x >> 6;
    const int row  = blockIdx.x * 4 + wid;
    if (row >= nrows) return;

    const float4* __restrict__ rp = reinterpret_cast<const float4*>(in) + (size_t)row * 256;
    f32x4* __restrict__ op        = reinterpret_cast<f32x4*>(out) + (size_t)row * 256;

    const float4 v0 = rp[lane];
    const float4 v1 = rp[64 + lane];
    const float4 v2 = rp[128 + lane];
    const float4 v3 = rp[192 + lane];

    float x0  = v0.x, x1  = v0.y, x2  = v0.z, x3  = v0.w;
    float x4  = v1.x, x5  = v1.y, x6  = v1.z, x7  = v1.w;
    float x8  = v2.x, x9  = v2.y, x10 = v2.z, x11 = v2.w;
    float x12 = v3.x, x13 = v3.y, x14 = v3.z, x15 = v3.w;

    // ---- per-lane max (tree) ----
    float h = fmaxf(fmaxf(fmaxf(fmaxf(x0, x1), fmaxf(x2, x3)),
                          fmaxf(fmaxf(x4, x5), fmaxf(x6, x7))),
                    fmaxf(fmaxf(fmaxf(x8, x9), fmaxf(x10, x11)),
                          fmaxf(fmaxf(x12, x13), fmaxf(x14, x15))));

    // ---- bitonic sort of 64 heads across lanes, ascending (lane 63 = max) ----
#pragma unroll
    for (int k = 2; k <= 64; k <<= 1) {
#pragma unroll
        for (int j = k >> 1; j > 0; j >>= 1) {
            const float p = __shfl_xor(h, j);
            const bool keep_min = (((lane & k) == 0) == ((lane & j) == 0));
            h = keep_min ? fminf(h, p) : fmaxf(h, p);
        }
    }
    const float t0 = __shfl(h, 48);   // 16th-largest head: lower bound on kth

    // ---- smallest candidate ----
    float m = FLT_MAX;
#define CANDMIN(X) m = fminf(m, ((X) >= t0) ? (X) : FLT_MAX);
    CANDMIN(x0)  CANDMIN(x1)  CANDMIN(x2)  CANDMIN(x3)
    CANDMIN(x4)  CANDMIN(x5)  CANDMIN(x6)  CANDMIN(x7)
    CANDMIN(x8)  CANDMIN(x9)  CANDMIN(x10) CANDMIN(x11)
    CANDMIN(x12) CANDMIN(x13) CANDMIN(x14) CANDMIN(x15)
#undef CANDMIN
    float g = wave_min64(m);

    // ---- ascend distinct candidate values until count(x > g) <= 15 ----
    for (;;) {
        int cnt = 0;
        float nm = FLT_MAX;
#define STEP(X) { const bool gt = (X) > g; cnt += gt ? 1 : 0; nm = fminf(nm, gt ? (X) : FLT_MAX); }
        STEP(x0)  STEP(x1)  STEP(x2)  STEP(x3)
        STEP(x4)  STEP(x5)  STEP(x6)  STEP(x7)
        STEP(x8)  STEP(x9)  STEP(x10) STEP(x11)
        STEP(x12) STEP(x13) STEP(x14) STEP(x15)
#undef STEP
        if (wave_sum64_i(cnt) <= 15) break;   // wave-uniform after full reduce
        g = wave_min64(nm);
    }
    const float kth = g;

    // ---- fused mask + sum + normalize + store ----
    x0  = (x0  >= kth) ? x0  : 0.0f;  x1  = (x1  >= kth) ? x1  : 0.0f;
    x2  = (x2  >= kth) ? x2  : 0.0f;  x3  = (x3  >= kth) ? x3  : 0.0f;
    x4  = (x4  >= kth) ? x4  : 0.0f;  x5  = (x5  >= kth) ? x5  : 0.0f;
    x6  = (x6  >= kth) ? x6  : 0.0f;  x7  = (x7  >= kth) ? x7  : 0.0f;
    x8  = (x8  >= kth) ? x8  : 0.0f;  x9  = (x9  >= kth) ? x9  : 0.0f;
    x10 = (x10 >= kth) ? x10 : 0.0f;  x11 = (x11 >= kth) ? x11 : 0.0f;
    x12 = (x12 >= kth) ? x12 : 0.0f;  x13 = (x13 >= kth) ? x13 : 0.0f;
    x14 = (x14 >= kth) ? x14 : 0.0f;  x15 = (x15 >= kth) ? x15 : 0.0f;

    float s = (((x0 + x1) + (x2 + x3)) + ((x4 + x5) + (x6 + x7)))
            + (((x8 + x9) + (x10 + x11)) + ((x12 + x13) + (x14 + x15)));
    s = wave_sum64(s);
    const float inv = 1.0f / s;

    f32x4 o;
    o.x = x0 * inv;  o.y = x1 * inv;  o.z = x2 * inv;  o.w = x3 * inv;
    __builtin_nontemporal_store(o, &op[lane]);
    o.x = x4 * inv;  o.y = x5 * inv;  o.z = x6 * inv;  o.w = x7 * inv;
    __builtin_nontemporal_store(o, &op[64 + lane]);
    o.x = x8 * inv;  o.y = x9 * inv;  o.z = x10 * inv; o.w = x11 * inv;
    __builtin_nontemporal_store(o, &op[128 + lane]);
    o.x = x12 * inv; o.y = x13 * inv; o.z = x14 * inv; o.w = x15 * inv;
    __builtin_nontemporal_store(o, &op[192 + lane]);
}

extern "C" void kernel_launch(void* const* d_in, const int* in_sizes, int n_in,
                              void* d_out, int out_size, void* d_ws, size_t ws_size,
                              hipStream_t stream) {
    (void)n_in; (void)d_ws; (void)ws_size; (void)out_size;
    const float* in = (const float*)d_in[0];
    float* out = (float*)d_out;
    const int nrows = in_sizes[0] / 1024;           // 16*4096 = 65536
    const int blocks = (nrows + 3) / 4;             // 4 waves (rows) per 256-thread block
    kmax_norm_kernel<<<blocks, 256, 0, stream>>>(in, out, nrows);
}

// Round 5
// 73.689 us; speedup vs baseline: 1.6810x; 1.0170x over previous
//
#include <hip/hip_runtime.h>
#include <cfloat>

// One 64-lane wave per row of 1024 floats; lane i owns j*256 + i*4 + {0..3}.
//
// kth selection, fast path (exact):
//   t0 = 1.84 (constant). C = count(x >= t0) over the row.
//   If 16 <= C <= 64: compact the C candidates into LDS (prefix-sum scatter),
//   one lane-wide bitonic sort of 64 (pad -inf), kth = sorted[48]
//   (rank-16-from-top; valid because C >= 16 and every top-16 value >= t0).
//   Else: fallback = per-lane-max head-sort for a row-derived t0', then
//   exact value-ascent (R3 algorithm).

typedef float f32x4 __attribute__((ext_vector_type(4)));

static __device__ __forceinline__ float wave_min64(float v) {
#pragma unroll
    for (int d = 1; d < 64; d <<= 1) v = fminf(v, __shfl_xor(v, d));
    return v;
}
static __device__ __forceinline__ float wave_sum64(float v) {
#pragma unroll
    for (int d = 1; d < 64; d <<= 1) v += __shfl_xor(v, d);
    return v;
}
static __device__ __forceinline__ int wave_sum64_i(int v) {
#pragma unroll
    for (int d = 1; d < 64; d <<= 1) v += __shfl_xor(v, d);
    return v;
}

__global__ __launch_bounds__(256) void kmax_norm_kernel(const float* __restrict__ in,
                                                        float* __restrict__ out,
                                                        int nrows) {
    __shared__ float sm[4][64];

    const int lane = threadIdx.x & 63;
    const int wid  = threadIdx.x >> 6;
    const int row  = blockIdx.x * 4 + wid;
    if (row >= nrows) return;

    const float4* __restrict__ rp = reinterpret_cast<const float4*>(in) + (size_t)row * 256;
    f32x4* __restrict__ op        = reinterpret_cast<f32x4*>(out) + (size_t)row * 256;

    const float4 v0 = rp[lane];
    const float4 v1 = rp[64 + lane];
    const float4 v2 = rp[128 + lane];
    const float4 v3 = rp[192 + lane];

    const float x0  = v0.x, x1  = v0.y, x2  = v0.z, x3  = v0.w;
    const float x4  = v1.x, x5  = v1.y, x6  = v1.z, x7  = v1.w;
    const float x8  = v2.x, x9  = v2.y, x10 = v2.z, x11 = v2.w;
    const float x12 = v3.x, x13 = v3.y, x14 = v3.z, x15 = v3.w;

    const float t0 = 1.84f;   // E[count >= t0] ~= 33 per row for N(0,1)

    // per-lane candidate count
    int c = 0;
#define CNT(X) c += ((X) >= t0) ? 1 : 0;
    CNT(x0)  CNT(x1)  CNT(x2)  CNT(x3)  CNT(x4)  CNT(x5)  CNT(x6)  CNT(x7)
    CNT(x8)  CNT(x9)  CNT(x10) CNT(x11) CNT(x12) CNT(x13) CNT(x14) CNT(x15)
#undef CNT

    // inclusive scan across lanes
    int pinc = c;
#pragma unroll
    for (int d = 1; d < 64; d <<= 1) {
        const int t = __shfl_up(pinc, d);
        if (lane >= d) pinc += t;
    }
    const int C = __shfl(pinc, 63);

    float kth;
    if (C >= 16 && C <= 64) {
        // ---- fast path: compact candidates to LDS, bitonic-sort 64 ----
        int idx = pinc - c;   // exclusive offset
#define SCAT(X) if ((X) >= t0) { sm[wid][idx] = (X); ++idx; }
        SCAT(x0)  SCAT(x1)  SCAT(x2)  SCAT(x3)  SCAT(x4)  SCAT(x5)  SCAT(x6)  SCAT(x7)
        SCAT(x8)  SCAT(x9)  SCAT(x10) SCAT(x11) SCAT(x12) SCAT(x13) SCAT(x14) SCAT(x15)
#undef SCAT
        float y = (lane < C) ? sm[wid][lane] : -FLT_MAX;
        // bitonic sort ascending across lanes (lane 63 = max)
#pragma unroll
        for (int k = 2; k <= 64; k <<= 1) {
#pragma unroll
            for (int j = k >> 1; j > 0; j >>= 1) {
                const float p = __shfl_xor(y, j);
                const bool keep_min = (((lane & k) == 0) == ((lane & j) == 0));
                y = keep_min ? fminf(y, p) : fmaxf(y, p);
            }
        }
        kth = __shfl(y, 48);   // 16th largest
    } else {
        // ---- fallback (rare, wave-uniform): head-sort + exact value ascent ----
        float h = fmaxf(fmaxf(fmaxf(fmaxf(x0, x1), fmaxf(x2, x3)),
                              fmaxf(fmaxf(x4, x5), fmaxf(x6, x7))),
                        fmaxf(fmaxf(fmaxf(x8, x9), fmaxf(x10, x11)),
                              fmaxf(fmaxf(x12, x13), fmaxf(x14, x15))));
#pragma unroll
        for (int k = 2; k <= 64; k <<= 1) {
#pragma unroll
            for (int j = k >> 1; j > 0; j >>= 1) {
                const float p = __shfl_xor(h, j);
                const bool keep_min = (((lane & k) == 0) == ((lane & j) == 0));
                h = keep_min ? fminf(h, p) : fmaxf(h, p);
            }
        }
        const float tl = __shfl(h, 48);   // 16th-largest head: lower bound on kth

        float m = FLT_MAX;
#define CANDMIN(X) m = fminf(m, ((X) >= tl) ? (X) : FLT_MAX);
        CANDMIN(x0)  CANDMIN(x1)  CANDMIN(x2)  CANDMIN(x3)
        CANDMIN(x4)  CANDMIN(x5)  CANDMIN(x6)  CANDMIN(x7)
        CANDMIN(x8)  CANDMIN(x9)  CANDMIN(x10) CANDMIN(x11)
        CANDMIN(x12) CANDMIN(x13) CANDMIN(x14) CANDMIN(x15)
#undef CANDMIN
        float g = wave_min64(m);
        for (;;) {
            int cnt = 0;
            float nm = FLT_MAX;
#define STEP(X) { const bool gt = (X) > g; cnt += gt ? 1 : 0; nm = fminf(nm, gt ? (X) : FLT_MAX); }
            STEP(x0)  STEP(x1)  STEP(x2)  STEP(x3)
            STEP(x4)  STEP(x5)  STEP(x6)  STEP(x7)
            STEP(x8)  STEP(x9)  STEP(x10) STEP(x11)
            STEP(x12) STEP(x13) STEP(x14) STEP(x15)
#undef STEP
            if (wave_sum64_i(cnt) <= 15) break;
            g = wave_min64(nm);
        }
        kth = g;
    }

    // ---- fused mask + sum + normalize + store ----
    const float z0  = (x0  >= kth) ? x0  : 0.0f;  const float z1  = (x1  >= kth) ? x1  : 0.0f;
    const float z2  = (x2  >= kth) ? x2  : 0.0f;  const float z3  = (x3  >= kth) ? x3  : 0.0f;
    const float z4  = (x4  >= kth) ? x4  : 0.0f;  const float z5  = (x5  >= kth) ? x5  : 0.0f;
    const float z6  = (x6  >= kth) ? x6  : 0.0f;  const float z7  = (x7  >= kth) ? x7  : 0.0f;
    const float z8  = (x8  >= kth) ? x8  : 0.0f;  const float z9  = (x9  >= kth) ? x9  : 0.0f;
    const float z10 = (x10 >= kth) ? x10 : 0.0f;  const float z11 = (x11 >= kth) ? x11 : 0.0f;
    const float z12 = (x12 >= kth) ? x12 : 0.0f;  const float z13 = (x13 >= kth) ? x13 : 0.0f;
    const float z14 = (x14 >= kth) ? x14 : 0.0f;  const float z15 = (x15 >= kth) ? x15 : 0.0f;

    float s = (((z0 + z1) + (z2 + z3)) + ((z4 + z5) + (z6 + z7)))
            + (((z8 + z9) + (z10 + z11)) + ((z12 + z13) + (z14 + z15)));
    s = wave_sum64(s);
    const float inv = 1.0f / s;

    f32x4 o;
    o.x = z0 * inv;  o.y = z1 * inv;  o.z = z2 * inv;  o.w = z3 * inv;
    __builtin_nontemporal_store(o, &op[lane]);
    o.x = z4 * inv;  o.y = z5 * inv;  o.z = z6 * inv;  o.w = z7 * inv;
    __builtin_nontemporal_store(o, &op[64 + lane]);
    o.x = z8 * inv;  o.y = z9 * inv;  o.z = z10 * inv; o.w = z11 * inv;
    __builtin_nontemporal_store(o, &op[128 + lane]);
    o.x = z12 * inv; o.y = z13 * inv; o.z = z14 * inv; o.w = z15 * inv;
    __builtin_nontemporal_store(o, &op[192 + lane]);
}

extern "C" void kernel_launch(void* const* d_in, const int* in_sizes, int n_in,
                              void* d_out, int out_size, void* d_ws, size_t ws_size,
                              hipStream_t stream) {
    (void)n_in; (void)d_ws; (void)ws_size; (void)out_size;
    const float* in = (const float*)d_in[0];
    float* out = (float*)d_out;
    const int nrows = in_sizes[0] / 1024;           // 16*4096 = 65536
    const int blocks = (nrows + 3) / 4;             // 4 waves (rows) per 256-thread block
    kmax_norm_kernel<<<blocks, 256, 0, stream>>>(in, out, nrows);
}